// Round 10
// baseline (298.801 us; speedup 1.0000x reference)
//
#include <hip/hip_runtime.h>
#include <math.h>

#define NWG  64
#define NTHR 512

// ws layout (floats). First 512 floats = flag slots (uint), zeroed below:
//   HN handshake (per-wg):  slot (layer*4+s)*16 + rb   -> 0..255
//   S2 (per-seq full):      slot 256 + layer*4 + s     -> 256..271
//   S3 (per-seq full):      slot 272 + layer*4 + s     -> 272..287
#define WS_HN 512                   // 256 rows x 128 (hn rows 1..3 of each wg)
#define WS_DT (WS_HN + 32768)       // 256 x 256
#define WS_DU (WS_DT + 65536)       // 256 x 256  (du = dt*u)
#define WS_BC (WS_DU + 65536)       // 256 x 32
#define WS_Y  (WS_BC + 8192)        // 256 x 256

__device__ __forceinline__ float silu_f(float v) { return v / (1.0f + __expf(-v)); }
__device__ __forceinline__ float dot4(float4 a, float4 b) {
    return a.x*b.x + a.y*b.y + a.z*b.z + a.w*b.w;
}
__device__ __forceinline__ float wave_red_sum(float v) {
    v += __shfl_xor(v, 1);  v += __shfl_xor(v, 2);  v += __shfl_xor(v, 4);
    v += __shfl_xor(v, 8);  v += __shfl_xor(v, 16); v += __shfl_xor(v, 32);
    return v;
}
// Agent-coherent scalar load: reads the coherence point (MALL), bypassing
// possibly-stale local L1/L2. No cache-wide invalidate.
__device__ __forceinline__ float aload(const float* p) {
    return __hip_atomic_load(p, __ATOMIC_RELAXED, __HIP_MEMORY_SCOPE_AGENT);
}
// Agent-coherent write-through store: lands at the coherence point, no
// buffer_wbl2 cache walk. vmcnt tracks completion.
__device__ __forceinline__ void astore(float* p, float v) {
    __hip_atomic_store(p, v, __ATOMIC_RELAXED, __HIP_MEMORY_SCOPE_AGENT);
}

// Full per-seq barrier (16 wgs), RELEASE-FREE protocol: cross-wg data was
// stored write-through; __syncthreads drains every wave's vmcnt to 0, so the
// data is at the coherence point before the relaxed flag bump.
__device__ __forceinline__ void seq_barrier(unsigned* slot) {
    __syncthreads();
    if (threadIdx.x == 0) {
        asm volatile("s_waitcnt vmcnt(0)" ::: "memory");
        __hip_atomic_fetch_add(slot, 1u, __ATOMIC_RELAXED, __HIP_MEMORY_SCOPE_AGENT);
        while (__hip_atomic_load(slot, __ATOMIC_RELAXED, __HIP_MEMORY_SCOPE_AGENT) < 16u)
            __builtin_amdgcn_s_sleep(1);
    }
    __syncthreads();
}

// 64 wgs x 512 threads, REGULAR launch (co-resident by capacity).
// seq = wg & 3, row-block rb = wg >> 2 : owns rows l0..l0+3 (l0 = rb*4).
// Register residual: thread t owns (row h = t>>7, col c = t&127).
__global__ __launch_bounds__(NTHR, 1) void fused_kernel(
    const float* __restrict__ mha_in, const int* __restrict__ mask,
    const float* __restrict__ mlp_w1, const float* __restrict__ mlp_b1,
    const float* __restrict__ mlp_w2, const float* __restrict__ mlp_b2,
    const float* __restrict__ in_proj_w, const float* __restrict__ conv_w,
    const float* __restrict__ conv_b, const float* __restrict__ x_proj_w,
    const float* __restrict__ dt_proj_w, const float* __restrict__ dt_proj_b,
    const float* __restrict__ A_log, const float* __restrict__ D_skip,
    const float* __restrict__ out_proj_w, const float* __restrict__ blk_norm_w,
    const float* __restrict__ norm_f_w,
    float* __restrict__ ws, float* __restrict__ out)
{
    const int wg = blockIdx.x;
    const int t  = threadIdx.x;
    const int s  = wg & 3;           // sequence
    const int rb = wg >> 2;          // row-block within seq (0..15)
    const int l0 = rb * 4;           // first owned local row
    const int r0 = s*64 + l0;        // first owned global row
    const int d0 = rb * 16;          // scan channel base
    const int h  = t >> 7;           // owned row 0..3
    const int c  = t & 127;          // owned col
    const int wave = t >> 6;

    unsigned* bar = (unsigned*)ws;
    float* hng = ws + WS_HN;
    float* dtg = ws + WS_DT;
    float* dug = ws + WS_DU;
    float* bcg = ws + WS_BC;
    float* yg  = ws + WS_Y;

    __shared__ float bufX[8][256];   // x rows l0-3..l0+3 (m = 0..6), all local
    __shared__ float hnH[3][128];    // neighbor hn rows (halo)
    __shared__ float bufZ[4][256];   // z (computed during scan window)
    __shared__ float bufA[4][256];   // h1 / u (kept live through gate)
    __shared__ float bufG[4][256];   // g = (y + u*Dsk)*silu(z)
    __shared__ float bufB[4][128];   // x_in / hn (own rows)
    __shared__ float xdS[4][40];
    __shared__ float sdt[64][17];    // staged dt   [l][ch]  (+1 pad: banks)
    __shared__ float sdu[64][17];    // staged dt*u [l][ch]
    __shared__ float sbc[64][33];    // staged B,C  [l][0..15=B,16..31=C]
    __shared__ float pOut[4][4][128];
    __shared__ float part[8];
    __shared__ int   anyv;

    float resid;

    // ===================== MLP preamble (row-local) =====================
    bufB[h][c] = mha_in[(size_t)s*524288 + (size_t)(l0 + h)*128 + c];
    __syncthreads();
    {
        const float* w = mlp_w1 + (size_t)c * 128;
        float acc = 0.f;
        #pragma unroll 16
        for (int k4 = 0; k4 < 32; ++k4)
            acc += dot4(*(const float4*)&bufB[h][k4*4], *(const float4*)&w[k4*4]);
        float v = acc + mlp_b1[c];
        v = 0.5f*v*(1.0f + erff(v*0.70710678118f));
        bufA[h][c] = v;
    }
    __syncthreads();
    {
        const float* w = mlp_w2 + (size_t)c * 128;
        float acc = 0.f;
        #pragma unroll 16
        for (int k4 = 0; k4 < 32; ++k4)
            acc += dot4(*(const float4*)&bufA[h][k4*4], *(const float4*)&w[k4*4]);
        resid = acc + mlp_b2[c];
    }
    __syncthreads();

    // ===================== layer loop =====================
    for (int layer = 0; layer < 4; ++layer) {
        unsigned* hnslot = bar + (layer*4 + s)*16;
        unsigned* s2slot = bar + 256 + layer*4 + s;
        unsigned* s3slot = bar + 272 + layer*4 + s;

        // ---- rmsnorm(resid) -> bufB (hn); publish rows 1..3 to hng ----
        {
            float sq = wave_red_sum(resid*resid);
            if ((t & 63) == 0) part[wave] = sq;
        }
        __syncthreads();
        {
            float sr = part[h*2] + part[h*2 + 1];
            float sc = rsqrtf(sr*(1.0f/128.0f) + 1e-5f);
            float hv = resid * sc * blk_norm_w[layer*128 + c];
            bufB[h][c] = hv;
            if (h >= 1) astore(&hng[(size_t)(r0 + h)*128 + c], hv);
        }
        __syncthreads();   // bufB complete; all waves' hng stores drained
        // ---- publish hn flag; poll neighbor's (set at its same point) ----
        if (t == 0) {
            asm volatile("s_waitcnt vmcnt(0)" ::: "memory");
            __hip_atomic_fetch_add(hnslot + rb, 1u, __ATOMIC_RELAXED, __HIP_MEMORY_SCOPE_AGENT);
            if (rb > 0) {
                while (__hip_atomic_load(hnslot + rb - 1, __ATOMIC_RELAXED, __HIP_MEMORY_SCOPE_AGENT) == 0u)
                    __builtin_amdgcn_s_sleep(1);
            }
        }
        __syncthreads();

        // ---- issue halo hn loads (latency hides under own-row GEMM) ----
        float hvH = 0.f;
        if (rb > 0 && t < 384)
            hvH = aload(&hng[(size_t)(r0 - 3 + (t >> 7))*128 + (t & 127)]);

        // ---- in-GEMM x own rows: cols 0..255, 2 rows/thread -> bufX[3..6] --
        {
            const int d = t & 255, hp = t >> 8;      // rows hp*2, hp*2+1
            const float* w = in_proj_w + ((size_t)layer*512 + d)*128;
            float a0 = 0.f, a1 = 0.f;
            #pragma unroll 16
            for (int k4 = 0; k4 < 32; ++k4) {
                float4 wv = *(const float4*)&w[k4*4];
                a0 += dot4(*(const float4*)&bufB[hp*2  ][k4*4], wv);
                a1 += dot4(*(const float4*)&bufB[hp*2+1][k4*4], wv);
            }
            bufX[3 + hp*2][d] = a0;
            bufX[4 + hp*2][d] = a1;
        }
        // park halo hn into LDS (load wait hidden behind the GEMM above)
        if (t < 384) hnH[t >> 7][t & 127] = hvH;     // rb==0: zeros
        __syncthreads();

        // ---- halo x-GEMM: 3 redundant rows -> bufX[0..2] (zeros if rb==0) --
        {
            const int d = t & 255, hp = t >> 8;      // row m = hp (0 or 1)
            const float* w = in_proj_w + ((size_t)layer*512 + d)*128;
            float a = 0.f;
            #pragma unroll 16
            for (int k4 = 0; k4 < 32; ++k4)
                a += dot4(*(const float4*)&hnH[hp][k4*4], *(const float4*)&w[k4*4]);
            bufX[hp][d] = a;
            if (t < 256) {                           // row m = 2, col t
                const float* w2 = in_proj_w + ((size_t)layer*512 + t)*128;
                float a2 = 0.f;
                #pragma unroll 16
                for (int k4 = 0; k4 < 32; ++k4)
                    a2 += dot4(*(const float4*)&hnH[2][k4*4], *(const float4*)&w2[k4*4]);
                bufX[2][t] = a2;
            }
        }
        __syncthreads();

        // ---- conv + silu -> u in bufA (pure LDS, branch-free) ----
        {
            int d = t & 255, half = t >> 8;           // local rows half*2, +1
            float4 cw = *(const float4*)&conv_w[((size_t)layer*256 + d)*4];
            float cb = conv_b[layer*256 + d];
            float x0 = bufX[half*2    ][d];
            float x1 = bufX[half*2 + 1][d];
            float x2 = bufX[half*2 + 2][d];
            float x3 = bufX[half*2 + 3][d];
            float x4 = bufX[half*2 + 4][d];
            bufA[half*2    ][d] = silu_f(cb + cw.x*x0 + cw.y*x1 + cw.z*x2 + cw.w*x3);
            bufA[half*2 + 1][d] = silu_f(cb + cw.x*x1 + cw.y*x2 + cw.z*x3 + cw.w*x4);
        }
        __syncthreads();

        // ---- xproj: xdbl[4][40], K=256 from LDS ; B,C -> bcg inline ----
        if (t < 160) {
            int rq = t & 3, jx = t >> 2;
            const float* xw = x_proj_w + ((size_t)layer*40 + jx)*256;
            float acc = 0.f;
            #pragma unroll 16
            for (int k4 = 0; k4 < 64; ++k4)
                acc += dot4(*(const float4*)&bufA[rq][k4*4], *(const float4*)&xw[k4*4]);
            xdS[rq][jx] = acc;
            if (jx >= 8)
                astore(&bcg[(size_t)(r0+rq)*32 + (jx-8)], acc);
        }
        __syncthreads();

        // ---- dt = softplus(...) ; write dt and du = dt*u (write-through) --
        {
            int d = t & 255, half = t >> 8;
            const float* dw = dt_proj_w + ((size_t)layer*256 + d)*8;
            float4 wa = *(const float4*)&dw[0];
            float4 wb = *(const float4*)&dw[4];
            float b = dt_proj_b[layer*256 + d];
            #pragma unroll
            for (int q = 0; q < 2; ++q) {
                int rloc = half*2 + q;
                float4 xa = *(const float4*)&xdS[rloc][0];
                float4 xb = *(const float4*)&xdS[rloc][4];
                float pre = b + dot4(xa, wa) + dot4(xb, wb);
                float sp = (pre > 20.f) ? pre : log1pf(__expf(pre));
                astore(&dtg[(size_t)(r0+rloc)*256 + d], sp);
                astore(&dug[(size_t)(r0+rloc)*256 + d], sp * bufA[rloc][d]);
            }
        }
        seq_barrier(s2slot);   // S2: dt, du, B, C at coherence point

        // ---- stage scan inputs (parallel, all 512 threads) ----
        if (t < 256) {
            int l = t >> 2, q = t & 3;
            const float* p = &dtg[(size_t)(s*64+l)*256 + d0 + q*4];
            sdt[l][q*4]   = aload(p);     sdt[l][q*4+1] = aload(p+1);
            sdt[l][q*4+2] = aload(p+2);   sdt[l][q*4+3] = aload(p+3);
        } else {
            int tt = t - 256; int l = tt >> 2, q = tt & 3;
            const float* p = &dug[(size_t)(s*64+l)*256 + d0 + q*4];
            sdu[l][q*4]   = aload(p);     sdu[l][q*4+1] = aload(p+1);
            sdu[l][q*4+2] = aload(p+2);   sdu[l][q*4+3] = aload(p+3);
        }
        {
            int l = t >> 3, q = t & 7;
            const float* p = &bcg[(size_t)(s*64+l)*32 + q*4];
            sbc[l][q*4]   = aload(p);     sbc[l][q*4+1] = aload(p+1);
            sbc[l][q*4+2] = aload(p+2);   sbc[l][q*4+3] = aload(p+3);
        }
        __syncthreads();

        // ---- scan window: waves 0-3 scan (1 state/lane); waves 4-7 z-GEMM --
        if (t < 256) {
            const int lane = t & 63, w4 = t >> 6;
            const int cl = lane >> 4, n = lane & 15;
            const int lch = w4*4 + cl;               // local channel 0..15
            const int d = d0 + lch;
            const float A = -__expf(A_log[((size_t)(layer*256 + d))*16 + n]);
            float hst = 0.f;
            #pragma unroll 4
            for (int l = 0; l < 64; ++l) {
                float dtv = sdt[l][lch];             // broadcast within group
                float duv = sdu[l][lch];
                float Bn  = sbc[l][n];
                float Cn  = sbc[l][16 + n];
                float dA  = __expf(dtv * A);
                hst = dA*hst + duv*Bn;
                float p = hst * Cn;
                p += __shfl_xor(p, 1);
                p += __shfl_xor(p, 2);
                p += __shfl_xor(p, 4);
                p += __shfl_xor(p, 8);
                if (n == 0) astore(&yg[(size_t)(s*64+l)*256 + d], p);
            }
        } else {
            // in-GEMM z-half: col dz, 4 rows, hn still in bufB
            const int dz = t - 256;
            const float* w = in_proj_w + ((size_t)layer*512 + 256 + dz)*128;
            float a0=0.f, a1=0.f, a2=0.f, a3=0.f;
            #pragma unroll 16
            for (int k4 = 0; k4 < 32; ++k4) {
                float4 wv = *(const float4*)&w[k4*4];
                a0 += dot4(*(const float4*)&bufB[0][k4*4], wv);
                a1 += dot4(*(const float4*)&bufB[1][k4*4], wv);
                a2 += dot4(*(const float4*)&bufB[2][k4*4], wv);
                a3 += dot4(*(const float4*)&bufB[3][k4*4], wv);
            }
            bufZ[0][dz] = a0;  bufZ[1][dz] = a1;
            bufZ[2][dz] = a2;  bufZ[3][dz] = a3;
        }
        seq_barrier(s3slot);   // S3: y at coherence point (+ bufZ via barrier)

        // ---- gate: g = (y + u*Dsk) * silu(z)  (u in bufA, z in bufZ) ----
        {
            int d = t & 255, half = t >> 8;
            float Dsk = D_skip[layer*256 + d];
            #pragma unroll
            for (int q = 0; q < 2; ++q) {
                int rloc = half*2 + q; int r = r0 + rloc;
                float z = bufZ[rloc][d];
                float yv = aload(&yg[(size_t)r*256 + d]) + bufA[rloc][d]*Dsk;
                bufG[rloc][d] = yv * silu_f(z);
            }
        }
        __syncthreads();

        // ---- out-GEMM, K split 4 ways, LDS reduce ----
        {
            const int cc = t & 127, kc = t >> 7;
            const float* w = out_proj_w + ((size_t)layer*128 + cc)*256 + kc*64;
            float p0=0.f, p1=0.f, p2=0.f, p3=0.f;
            #pragma unroll
            for (int k4 = 0; k4 < 16; ++k4) {
                float4 wv = *(const float4*)&w[k4*4];
                p0 += dot4(*(const float4*)&bufG[0][kc*64 + k4*4], wv);
                p1 += dot4(*(const float4*)&bufG[1][kc*64 + k4*4], wv);
                p2 += dot4(*(const float4*)&bufG[2][kc*64 + k4*4], wv);
                p3 += dot4(*(const float4*)&bufG[3][kc*64 + k4*4], wv);
            }
            pOut[kc][0][cc] = p0;  pOut[kc][1][cc] = p1;
            pOut[kc][2][cc] = p2;  pOut[kc][3][cc] = p3;
        }
        __syncthreads();
        resid += pOut[0][h][c] + pOut[1][h][c] + pOut[2][h][c] + pOut[3][h][c];
        __syncthreads();
    }

    // ===================== final: row 63 of each seq =====================
    if (t == 0) anyv = 0;
    __syncthreads();
    if (rb == 15) {
        if (t < 64 && mask[s*4096 + t] != 0) anyv = 1;   // benign race
        float sq = wave_red_sum(resid*resid);
        if ((t & 63) == 0) part[wave] = sq;
    }
    __syncthreads();
    if (rb == 15 && h == 3) {
        float sr = part[6] + part[7];
        float sc = rsqrtf(sr*(1.0f/128.0f) + 1e-5f);
        float o  = resid * sc * norm_f_w[c];
        out[s*128 + c] = anyv ? o : 0.f;
    }
}

// ---------------------------------------------------------------------------
extern "C" void kernel_launch(void* const* d_in, const int* in_sizes, int n_in,
                              void* d_out, int out_size, void* d_ws, size_t ws_size,
                              hipStream_t stream) {
    (void)in_sizes; (void)n_in; (void)out_size; (void)ws_size;
    const float* mha_in     = (const float*)d_in[0];
    const int*   mask       = (const int*)  d_in[1];
    const float* mlp_w1     = (const float*)d_in[2];
    const float* mlp_b1     = (const float*)d_in[3];
    const float* mlp_w2     = (const float*)d_in[4];
    const float* mlp_b2     = (const float*)d_in[5];
    const float* in_proj_w  = (const float*)d_in[6];
    const float* conv_w     = (const float*)d_in[7];
    const float* conv_b     = (const float*)d_in[8];
    const float* x_proj_w   = (const float*)d_in[9];
    const float* dt_proj_w  = (const float*)d_in[10];
    const float* dt_proj_b  = (const float*)d_in[11];
    const float* A_log      = (const float*)d_in[12];
    const float* D_skip     = (const float*)d_in[13];
    const float* out_proj_w = (const float*)d_in[14];
    const float* blk_norm_w = (const float*)d_in[15];
    const float* norm_f_w   = (const float*)d_in[16];
    float* ws  = (float*)d_ws;
    float* out = (float*)d_out;

    // zero the flag slots (graph-capture-safe)
    hipMemsetAsync(d_ws, 0, 2048, stream);

    fused_kernel<<<NWG, NTHR, 0, stream>>>(
        mha_in, mask, mlp_w1, mlp_b1, mlp_w2, mlp_b2,
        in_proj_w, conv_w, conv_b, x_proj_w, dt_proj_w, dt_proj_b,
        A_log, D_skip, out_proj_w, blk_norm_w, norm_f_w, ws, out);
}

// Round 11
// 210.006 us; speedup vs baseline: 1.4228x; 1.4228x over previous
//
#include <hip/hip_runtime.h>
#include <math.h>

#define NWG  64
#define NTHR 512

// ws layout (floats). First 512 floats = barrier flag slots (uint), zeroed by
// the hipMemsetAsync below:
//   S1 (per-wg xg handshake): slot (layer*4+s)*16 + rb          -> 0..255
//   S2 (per-seq full):        slot 256 + layer*4 + s            -> 256..271
//   S3 (per-seq full):        slot 272 + layer*4 + s            -> 272..287
#define WS_XG 512                   // 256 rows x 256 (x-half of in_proj output)
#define WS_DT (WS_XG + 65536)       // 256 x 256
#define WS_DU (WS_DT + 65536)       // 256 x 256  (du = dt*u)
#define WS_BC (WS_DU + 65536)       // 256 x 32
#define WS_Y  (WS_BC + 8192)        // 256 x 256

__device__ __forceinline__ float silu_f(float v) { return v / (1.0f + __expf(-v)); }
__device__ __forceinline__ float dot4(float4 a, float4 b) {
    return a.x*b.x + a.y*b.y + a.z*b.z + a.w*b.w;
}
__device__ __forceinline__ float wave_red_sum(float v) {
    v += __shfl_xor(v, 1);  v += __shfl_xor(v, 2);  v += __shfl_xor(v, 4);
    v += __shfl_xor(v, 8);  v += __shfl_xor(v, 16); v += __shfl_xor(v, 32);
    return v;
}
// 8-lane butterfly reduce: all 8 lanes of the group end with the sum.
__device__ __forceinline__ float red8(float v) {
    v += __shfl_xor(v, 1);  v += __shfl_xor(v, 2);  v += __shfl_xor(v, 4);
    return v;
}
// select acc[ln] without dynamic indexing (rule: runtime-indexed arrays spill)
__device__ __forceinline__ float sel4(int ln, float a0, float a1, float a2, float a3) {
    return ln==0 ? a0 : (ln==1 ? a1 : (ln==2 ? a2 : a3));
}
// Agent-coherent scalar load: reads the coherence point (MALL), bypassing
// possibly-stale local L1/L2. No cache-wide invalidate.
__device__ __forceinline__ float aload(const float* p) {
    return __hip_atomic_load(p, __ATOMIC_RELAXED, __HIP_MEMORY_SCOPE_AGENT);
}
// Agent-coherent write-through store: lands at the coherence point, no
// buffer_wbl2 cache walk. vmcnt tracks completion.
__device__ __forceinline__ void astore(float* p, float v) {
    __hip_atomic_store(p, v, __ATOMIC_RELAXED, __HIP_MEMORY_SCOPE_AGENT);
}

// Full per-seq barrier (16 wgs), RELEASE-FREE protocol: cross-wg data was
// stored write-through; __syncthreads drains every wave's vmcnt to 0, so the
// data is at the coherence point before the relaxed flag bump.
__device__ __forceinline__ void seq_barrier(unsigned* slot) {
    __syncthreads();
    if (threadIdx.x == 0) {
        asm volatile("s_waitcnt vmcnt(0)" ::: "memory");
        __hip_atomic_fetch_add(slot, 1u, __ATOMIC_RELAXED, __HIP_MEMORY_SCOPE_AGENT);
        while (__hip_atomic_load(slot, __ATOMIC_RELAXED, __HIP_MEMORY_SCOPE_AGENT) < 16u)
            __builtin_amdgcn_s_sleep(1);
    }
    __syncthreads();
}

// 64 wgs x 512 threads, REGULAR launch (co-resident by capacity: 64 wgs <=
// 256 CUs at 1-wg/CU resources -> spin barriers deadlock-free).
// seq = wg & 3, row-block rb = wg >> 2 : owns rows l0..l0+3 (l0 = rb*4).
// Register residual: thread t owns (row h = t>>7, col c = t&127).
// GEMM phases use 8-lane-group k-split: lane ln of group g reads
// W[j][ln*4 + 32*i] -> 128 B contiguous per 8-lane group per step (16 lines
// per wave-load instead of 64), weights read exactly once.
__global__ __launch_bounds__(NTHR, 1) void fused_kernel(
    const float* __restrict__ mha_in, const int* __restrict__ mask,
    const float* __restrict__ mlp_w1, const float* __restrict__ mlp_b1,
    const float* __restrict__ mlp_w2, const float* __restrict__ mlp_b2,
    const float* __restrict__ in_proj_w, const float* __restrict__ conv_w,
    const float* __restrict__ conv_b, const float* __restrict__ x_proj_w,
    const float* __restrict__ dt_proj_w, const float* __restrict__ dt_proj_b,
    const float* __restrict__ A_log, const float* __restrict__ D_skip,
    const float* __restrict__ out_proj_w, const float* __restrict__ blk_norm_w,
    const float* __restrict__ norm_f_w,
    float* __restrict__ ws, float* __restrict__ out)
{
    const int wg = blockIdx.x;
    const int t  = threadIdx.x;
    const int s  = wg & 3;           // sequence
    const int rb = wg >> 2;          // row-block within seq (0..15)
    const int l0 = rb * 4;           // first owned local row
    const int r0 = s*64 + l0;        // first owned global row
    const int d0 = rb * 16;          // scan channel base
    const int h  = t >> 7;           // owned row 0..3
    const int c  = t & 127;          // owned col
    const int wave = t >> 6;
    const int grp = t >> 3, ln = t & 7;   // GEMM group / lane-in-group

    unsigned* bar = (unsigned*)ws;
    float* xg  = ws + WS_XG;
    float* dtg = ws + WS_DT;
    float* dug = ws + WS_DU;
    float* bcg = ws + WS_BC;
    float* yg  = ws + WS_Y;

    __shared__ float bufX[4][256];   // x (conv input, own rows)
    __shared__ float bufZ[4][256];   // z (computed during scan window)
    __shared__ float bufA[4][256];   // h1 / u (kept live through gate)
    __shared__ float bufG[4][256];   // g = (y + u*Dsk)*silu(z)
    __shared__ float bufB[4][128];   // x_in / hn (own rows)
    __shared__ float bufR[4][128];   // MLP h2 / out-GEMM result rows
    __shared__ float xdS[4][40];
    __shared__ float sdt[64][17];    // staged dt   [l][ch]  (+1 pad: banks)
    __shared__ float sdu[64][17];    // staged dt*u [l][ch]
    __shared__ float sbc[64][33];    // staged B,C  [l][0..15=B,16..31=C]
    __shared__ float part[8];
    __shared__ int   anyv;

    float resid;

    // ===================== MLP preamble (row-local) =====================
    bufB[h][c] = mha_in[(size_t)s*524288 + (size_t)(l0 + h)*128 + c];
    __syncthreads();
    // ---- h1 = gelu(x @ w1^T + b1), coalesced 8-lane groups ----
    {
        #pragma unroll
        for (int pass = 0; pass < 2; ++pass) {
            const int j = pass*64 + grp;
            const float* w = mlp_w1 + (size_t)j*128 + ln*4;
            float4 wv[4];
            #pragma unroll
            for (int i = 0; i < 4; ++i) wv[i] = *(const float4*)&w[i*32];
            float a0=0.f, a1=0.f, a2=0.f, a3=0.f;
            #pragma unroll
            for (int i = 0; i < 4; ++i) {
                a0 += dot4(*(const float4*)&bufB[0][ln*4 + i*32], wv[i]);
                a1 += dot4(*(const float4*)&bufB[1][ln*4 + i*32], wv[i]);
                a2 += dot4(*(const float4*)&bufB[2][ln*4 + i*32], wv[i]);
                a3 += dot4(*(const float4*)&bufB[3][ln*4 + i*32], wv[i]);
            }
            a0 = red8(a0); a1 = red8(a1); a2 = red8(a2); a3 = red8(a3);
            if (ln < 4) {
                float v = sel4(ln, a0, a1, a2, a3) + mlp_b1[j];
                bufA[ln][j] = 0.5f*v*(1.0f + erff(v*0.70710678118f));
            }
        }
    }
    __syncthreads();
    // ---- h2 = h1 @ w2^T + b2 -> bufR; resid = bufR[h][c] ----
    {
        #pragma unroll
        for (int pass = 0; pass < 2; ++pass) {
            const int j = pass*64 + grp;
            const float* w = mlp_w2 + (size_t)j*128 + ln*4;
            float4 wv[4];
            #pragma unroll
            for (int i = 0; i < 4; ++i) wv[i] = *(const float4*)&w[i*32];
            float a0=0.f, a1=0.f, a2=0.f, a3=0.f;
            #pragma unroll
            for (int i = 0; i < 4; ++i) {
                a0 += dot4(*(const float4*)&bufA[0][ln*4 + i*32], wv[i]);
                a1 += dot4(*(const float4*)&bufA[1][ln*4 + i*32], wv[i]);
                a2 += dot4(*(const float4*)&bufA[2][ln*4 + i*32], wv[i]);
                a3 += dot4(*(const float4*)&bufA[3][ln*4 + i*32], wv[i]);
            }
            a0 = red8(a0); a1 = red8(a1); a2 = red8(a2); a3 = red8(a3);
            if (ln < 4)
                bufR[ln][j] = sel4(ln, a0, a1, a2, a3) + mlp_b2[j];
        }
    }
    __syncthreads();
    resid = bufR[h][c];
    __syncthreads();

    // ===================== layer loop =====================
    for (int layer = 0; layer < 4; ++layer) {
        unsigned* s1slot = bar + (layer*4 + s)*16;
        unsigned* s2slot = bar + 256 + layer*4 + s;
        unsigned* s3slot = bar + 272 + layer*4 + s;

        // ---- rmsnorm(resid) -> bufB (hn) ----
        {
            float sq = wave_red_sum(resid*resid);
            if ((t & 63) == 0) part[wave] = sq;
        }
        __syncthreads();
        {
            float sr = part[h*2] + part[h*2 + 1];
            float sc = rsqrtf(sr*(1.0f/128.0f) + 1e-5f);
            bufB[h][c] = resid * sc * blk_norm_w[layer*128 + c];
        }
        __syncthreads();

        // ---- in-GEMM x-half: coalesced groups, cols 0..255 -> bufX + xg ----
        {
            #pragma unroll
            for (int pass = 0; pass < 4; ++pass) {
                const int j = pass*64 + grp;
                const float* w = in_proj_w + ((size_t)layer*512 + j)*128 + ln*4;
                float4 wv[4];
                #pragma unroll
                for (int i = 0; i < 4; ++i) wv[i] = *(const float4*)&w[i*32];
                float a0=0.f, a1=0.f, a2=0.f, a3=0.f;
                #pragma unroll
                for (int i = 0; i < 4; ++i) {
                    a0 += dot4(*(const float4*)&bufB[0][ln*4 + i*32], wv[i]);
                    a1 += dot4(*(const float4*)&bufB[1][ln*4 + i*32], wv[i]);
                    a2 += dot4(*(const float4*)&bufB[2][ln*4 + i*32], wv[i]);
                    a3 += dot4(*(const float4*)&bufB[3][ln*4 + i*32], wv[i]);
                }
                a0 = red8(a0); a1 = red8(a1); a2 = red8(a2); a3 = red8(a3);
                if (ln < 4) {
                    float v = sel4(ln, a0, a1, a2, a3);
                    bufX[ln][j] = v;
                    astore(&xg[(size_t)(r0 + ln)*256 + j], v);  // halo for rb+1
                }
            }
        }
        // ---- S1: neighbor handshake (conv needs wg rb-1's last 3 rows) ----
        __syncthreads();   // drains all waves' vmcnt -> xg stores at MALL
        if (t == 0) {
            asm volatile("s_waitcnt vmcnt(0)" ::: "memory");
            __hip_atomic_fetch_add(s1slot + rb, 1u, __ATOMIC_RELAXED, __HIP_MEMORY_SCOPE_AGENT);
            if (rb > 0) {
                while (__hip_atomic_load(s1slot + rb - 1, __ATOMIC_RELAXED, __HIP_MEMORY_SCOPE_AGENT) == 0u)
                    __builtin_amdgcn_s_sleep(1);
            }
        }
        __syncthreads();

        // ---- conv + silu -> u in bufA (own rows from LDS, halo via aload) --
        {
            int d = t & 255, half = t >> 8;           // 2 rows per thread
            int rbase = s*64;
            float4 cw = *(const float4*)&conv_w[((size_t)layer*256 + d)*4];
            float cb = conv_b[layer*256 + d];
            if (half == 0) {
                float x0 = (l0-3 >= 0) ? aload(&xg[(size_t)(rbase+l0-3)*256 + d]) : 0.f;
                float x1 = (l0-2 >= 0) ? aload(&xg[(size_t)(rbase+l0-2)*256 + d]) : 0.f;
                float x2 = (l0-1 >= 0) ? aload(&xg[(size_t)(rbase+l0-1)*256 + d]) : 0.f;
                float x3 = bufX[0][d];
                float x4 = bufX[1][d];
                bufA[0][d] = silu_f(cb + cw.x*x0 + cw.y*x1 + cw.z*x2 + cw.w*x3);
                bufA[1][d] = silu_f(cb + cw.x*x1 + cw.y*x2 + cw.z*x3 + cw.w*x4);
            } else {
                float x0 = (l0-1 >= 0) ? aload(&xg[(size_t)(rbase+l0-1)*256 + d]) : 0.f;
                float x1 = bufX[0][d];
                float x2 = bufX[1][d];
                float x3 = bufX[2][d];
                float x4 = bufX[3][d];
                bufA[2][d] = silu_f(cb + cw.x*x0 + cw.y*x1 + cw.z*x2 + cw.w*x3);
                bufA[3][d] = silu_f(cb + cw.x*x1 + cw.y*x2 + cw.z*x3 + cw.w*x4);
            }
        }
        __syncthreads();

        // ---- xproj: coalesced groups, 40 cols, K=256 ; B,C -> bcg inline ---
        if (t < 320) {
            const int jx = grp;                       // 0..39
            const float* xw = x_proj_w + ((size_t)layer*40 + jx)*256 + ln*4;
            float4 wv[8];
            #pragma unroll
            for (int i = 0; i < 8; ++i) wv[i] = *(const float4*)&xw[i*32];
            float a0=0.f, a1=0.f, a2=0.f, a3=0.f;
            #pragma unroll
            for (int i = 0; i < 8; ++i) {
                a0 += dot4(*(const float4*)&bufA[0][ln*4 + i*32], wv[i]);
                a1 += dot4(*(const float4*)&bufA[1][ln*4 + i*32], wv[i]);
                a2 += dot4(*(const float4*)&bufA[2][ln*4 + i*32], wv[i]);
                a3 += dot4(*(const float4*)&bufA[3][ln*4 + i*32], wv[i]);
            }
            a0 = red8(a0); a1 = red8(a1); a2 = red8(a2); a3 = red8(a3);
            if (ln < 4) {
                float v = sel4(ln, a0, a1, a2, a3);
                xdS[ln][jx] = v;
                if (jx >= 8)
                    astore(&bcg[(size_t)(r0+ln)*32 + (jx-8)], v);
            }
        }
        __syncthreads();

        // ---- dt = softplus(...) ; write dt and du = dt*u (write-through) --
        {
            int d = t & 255, half = t >> 8;
            const float* dw = dt_proj_w + ((size_t)layer*256 + d)*8;
            float4 wa = *(const float4*)&dw[0];
            float4 wb = *(const float4*)&dw[4];
            float b = dt_proj_b[layer*256 + d];
            #pragma unroll
            for (int q = 0; q < 2; ++q) {
                int rloc = half*2 + q;
                float4 xa = *(const float4*)&xdS[rloc][0];
                float4 xb = *(const float4*)&xdS[rloc][4];
                float pre = b + dot4(xa, wa) + dot4(xb, wb);
                float sp = (pre > 20.f) ? pre : log1pf(__expf(pre));
                astore(&dtg[(size_t)(r0+rloc)*256 + d], sp);
                astore(&dug[(size_t)(r0+rloc)*256 + d], sp * bufA[rloc][d]);
            }
        }
        seq_barrier(s2slot);   // S2: dt, du, B, C at coherence point

        // ---- stage scan inputs (parallel, all 512 threads) ----
        if (t < 256) {
            int l = t >> 2, q = t & 3;
            const float* p = &dtg[(size_t)(s*64+l)*256 + d0 + q*4];
            sdt[l][q*4]   = aload(p);     sdt[l][q*4+1] = aload(p+1);
            sdt[l][q*4+2] = aload(p+2);   sdt[l][q*4+3] = aload(p+3);
        } else {
            int tt = t - 256; int l = tt >> 2, q = tt & 3;
            const float* p = &dug[(size_t)(s*64+l)*256 + d0 + q*4];
            sdu[l][q*4]   = aload(p);     sdu[l][q*4+1] = aload(p+1);
            sdu[l][q*4+2] = aload(p+2);   sdu[l][q*4+3] = aload(p+3);
        }
        {
            int l = t >> 3, q = t & 7;
            const float* p = &bcg[(size_t)(s*64+l)*32 + q*4];
            sbc[l][q*4]   = aload(p);     sbc[l][q*4+1] = aload(p+1);
            sbc[l][q*4+2] = aload(p+2);   sbc[l][q*4+3] = aload(p+3);
        }
        __syncthreads();

        // ---- scan window: wave0 scans ; waves 4-7 z-GEMM (coalesced) ----
        if (t < 64) {
            const int dloc = t >> 2, sub = t & 3, d = d0 + dloc;
            const float* Ab = A_log + ((size_t)layer*256 + d)*16 + sub*4;
            float A0 = -__expf(Ab[0]), A1 = -__expf(Ab[1]);
            float A2 = -__expf(Ab[2]), A3 = -__expf(Ab[3]);
            float h0 = 0.f, h1v = 0.f, h2v = 0.f, h3v = 0.f;
            #pragma unroll 4
            for (int l = 0; l < 64; ++l) {
                float dtv = sdt[l][dloc];
                float duv = sdu[l][dloc];
                float4 B4, C4;
                B4.x = sbc[l][sub*4];      B4.y = sbc[l][sub*4+1];
                B4.z = sbc[l][sub*4+2];    B4.w = sbc[l][sub*4+3];
                C4.x = sbc[l][16+sub*4];   C4.y = sbc[l][16+sub*4+1];
                C4.z = sbc[l][16+sub*4+2]; C4.w = sbc[l][16+sub*4+3];
                float dA, yp;
                dA = __expf(dtv*A0); h0  = dA*h0  + duv*B4.x; yp  = h0 *C4.x;
                dA = __expf(dtv*A1); h1v = dA*h1v + duv*B4.y; yp += h1v*C4.y;
                dA = __expf(dtv*A2); h2v = dA*h2v + duv*B4.z; yp += h2v*C4.z;
                dA = __expf(dtv*A3); h3v = dA*h3v + duv*B4.w; yp += h3v*C4.w;
                yp += __shfl_xor(yp, 1);
                yp += __shfl_xor(yp, 2);
                if (sub == 0) astore(&yg[(size_t)(s*64+l)*256 + d], yp);
            }
        } else if (t >= 256) {
            // in-GEMM z-half: coalesced groups over cols 256..511
            const int tz = t - 256, gz = tz >> 3, lz = tz & 7;   // 32 groups
            #pragma unroll 2
            for (int pass = 0; pass < 8; ++pass) {
                const int j = pass*32 + gz;          // z col 0..255
                const float* w = in_proj_w + ((size_t)layer*512 + 256 + j)*128 + lz*4;
                float4 wv[4];
                #pragma unroll
                for (int i = 0; i < 4; ++i) wv[i] = *(const float4*)&w[i*32];
                float a0=0.f, a1=0.f, a2=0.f, a3=0.f;
                #pragma unroll
                for (int i = 0; i < 4; ++i) {
                    a0 += dot4(*(const float4*)&bufB[0][lz*4 + i*32], wv[i]);
                    a1 += dot4(*(const float4*)&bufB[1][lz*4 + i*32], wv[i]);
                    a2 += dot4(*(const float4*)&bufB[2][lz*4 + i*32], wv[i]);
                    a3 += dot4(*(const float4*)&bufB[3][lz*4 + i*32], wv[i]);
                }
                a0 += __shfl_xor(a0, 1); a0 += __shfl_xor(a0, 2); a0 += __shfl_xor(a0, 4);
                a1 += __shfl_xor(a1, 1); a1 += __shfl_xor(a1, 2); a1 += __shfl_xor(a1, 4);
                a2 += __shfl_xor(a2, 1); a2 += __shfl_xor(a2, 2); a2 += __shfl_xor(a2, 4);
                a3 += __shfl_xor(a3, 1); a3 += __shfl_xor(a3, 2); a3 += __shfl_xor(a3, 4);
                if (lz < 4)
                    bufZ[lz][j] = sel4(lz, a0, a1, a2, a3);
            }
        }
        seq_barrier(s3slot);   // S3: y at coherence point (+ bufZ via barrier)

        // ---- gate: g = (y + u*Dsk) * silu(z)  (u in bufA, z in bufZ) ----
        {
            int d = t & 255, half = t >> 8;
            float Dsk = D_skip[layer*256 + d];
            #pragma unroll
            for (int q = 0; q < 2; ++q) {
                int rloc = half*2 + q; int r = r0 + rloc;
                float z = bufZ[rloc][d];
                float yv = aload(&yg[(size_t)r*256 + d]) + bufA[rloc][d]*Dsk;
                bufG[rloc][d] = yv * silu_f(z);
            }
        }
        __syncthreads();

        // ---- out-GEMM: coalesced groups, 128 cols, K=256 -> bufR ----
        {
            #pragma unroll
            for (int pass = 0; pass < 2; ++pass) {
                const int j = pass*64 + grp;         // col 0..127
                const float* w = out_proj_w + ((size_t)layer*128 + j)*256 + ln*4;
                float4 wv[8];
                #pragma unroll
                for (int i = 0; i < 8; ++i) wv[i] = *(const float4*)&w[i*32];
                float a0=0.f, a1=0.f, a2=0.f, a3=0.f;
                #pragma unroll
                for (int i = 0; i < 8; ++i) {
                    a0 += dot4(*(const float4*)&bufG[0][ln*4 + i*32], wv[i]);
                    a1 += dot4(*(const float4*)&bufG[1][ln*4 + i*32], wv[i]);
                    a2 += dot4(*(const float4*)&bufG[2][ln*4 + i*32], wv[i]);
                    a3 += dot4(*(const float4*)&bufG[3][ln*4 + i*32], wv[i]);
                }
                a0 = red8(a0); a1 = red8(a1); a2 = red8(a2); a3 = red8(a3);
                if (ln < 4)
                    bufR[ln][j] = sel4(ln, a0, a1, a2, a3);
            }
        }
        __syncthreads();
        resid += bufR[h][c];
        __syncthreads();
    }

    // ===================== final: row 63 of each seq =====================
    if (t == 0) anyv = 0;
    __syncthreads();
    if (rb == 15) {
        if (t < 64 && mask[s*4096 + t] != 0) anyv = 1;   // benign race
        float sq = wave_red_sum(resid*resid);
        if ((t & 63) == 0) part[wave] = sq;
    }
    __syncthreads();
    if (rb == 15 && h == 3) {
        float sr = part[6] + part[7];
        float sc = rsqrtf(sr*(1.0f/128.0f) + 1e-5f);
        float o  = resid * sc * norm_f_w[c];
        out[s*128 + c] = anyv ? o : 0.f;
    }
}

// ---------------------------------------------------------------------------
extern "C" void kernel_launch(void* const* d_in, const int* in_sizes, int n_in,
                              void* d_out, int out_size, void* d_ws, size_t ws_size,
                              hipStream_t stream) {
    (void)in_sizes; (void)n_in; (void)out_size; (void)ws_size;
    const float* mha_in     = (const float*)d_in[0];
    const int*   mask       = (const int*)  d_in[1];
    const float* mlp_w1     = (const float*)d_in[2];
    const float* mlp_b1     = (const float*)d_in[3];
    const float* mlp_w2     = (const float*)d_in[4];
    const float* mlp_b2     = (const float*)d_in[5];
    const float* in_proj_w  = (const float*)d_in[6];
    const float* conv_w     = (const float*)d_in[7];
    const float* conv_b     = (const float*)d_in[8];
    const float* x_proj_w   = (const float*)d_in[9];
    const float* dt_proj_w  = (const float*)d_in[10];
    const float* dt_proj_b  = (const float*)d_in[11];
    const float* A_log      = (const float*)d_in[12];
    const float* D_skip     = (const float*)d_in[13];
    const float* out_proj_w = (const float*)d_in[14];
    const float* blk_norm_w = (const float*)d_in[15];
    const float* norm_f_w   = (const float*)d_in[16];
    float* ws  = (float*)d_ws;
    float* out = (float*)d_out;

    // zero the barrier flag slots (graph-capture-safe)
    hipMemsetAsync(d_ws, 0, 2048, stream);

    fused_kernel<<<NWG, NTHR, 0, stream>>>(
        mha_in, mask, mlp_w1, mlp_b1, mlp_w2, mlp_b2,
        in_proj_w, conv_w, conv_b, x_proj_w, dt_proj_w, dt_proj_b,
        A_log, D_skip, out_proj_w, blk_norm_w, norm_f_w, ws, out);
}

// Round 12
// 204.248 us; speedup vs baseline: 1.4629x; 1.0282x over previous
//
#include <hip/hip_runtime.h>
#include <math.h>

#define NWG  64
#define NTHR 512

// ws layout (floats). First 512 floats = barrier flag slots (uint), zeroed by
// the hipMemsetAsync below:
//   S1 (per-wg xg handshake): slot (layer*4+s)*16 + rb          -> 0..255
//   S2 (per-seq full):        slot 256 + layer*4 + s            -> 256..271
//   S3 (per-seq full):        slot 272 + layer*4 + s            -> 272..287
#define WS_XG 512                   // 256 rows x 256 (x-half of in_proj output)
#define WS_DT (WS_XG + 65536)       // 256 x 256
#define WS_DU (WS_DT + 65536)       // 256 x 256  (du = dt*u)
#define WS_BC (WS_DU + 65536)       // 256 x 32
#define WS_Y  (WS_BC + 8192)        // 256 x 256

__device__ __forceinline__ float silu_f(float v) { return v / (1.0f + __expf(-v)); }
__device__ __forceinline__ float dot4(float4 a, float4 b) {
    return a.x*b.x + a.y*b.y + a.z*b.z + a.w*b.w;
}
__device__ __forceinline__ float wave_red_sum(float v) {
    v += __shfl_xor(v, 1);  v += __shfl_xor(v, 2);  v += __shfl_xor(v, 4);
    v += __shfl_xor(v, 8);  v += __shfl_xor(v, 16); v += __shfl_xor(v, 32);
    return v;
}
// 8-lane butterfly reduce: all 8 lanes of the group end with the sum.
__device__ __forceinline__ float red8(float v) {
    v += __shfl_xor(v, 1);  v += __shfl_xor(v, 2);  v += __shfl_xor(v, 4);
    return v;
}
// select acc[ln] without dynamic indexing (rule: runtime-indexed arrays spill)
__device__ __forceinline__ float sel4(int ln, float a0, float a1, float a2, float a3) {
    return ln==0 ? a0 : (ln==1 ? a1 : (ln==2 ? a2 : a3));
}
// Agent-coherent scalar load: reads the coherence point (MALL), bypassing
// possibly-stale local L1/L2. No cache-wide invalidate.
__device__ __forceinline__ float aload(const float* p) {
    return __hip_atomic_load(p, __ATOMIC_RELAXED, __HIP_MEMORY_SCOPE_AGENT);
}
// Agent-coherent write-through store: lands at the coherence point, no
// buffer_wbl2 cache walk. vmcnt tracks completion.
__device__ __forceinline__ void astore(float* p, float v) {
    __hip_atomic_store(p, v, __ATOMIC_RELAXED, __HIP_MEMORY_SCOPE_AGENT);
}

// Full per-seq barrier (16 wgs), RELEASE-FREE protocol: cross-wg data was
// stored write-through; __syncthreads drains every wave's vmcnt to 0, so the
// data is at the coherence point before the relaxed flag bump.
__device__ __forceinline__ void seq_barrier(unsigned* slot) {
    __syncthreads();
    if (threadIdx.x == 0) {
        asm volatile("s_waitcnt vmcnt(0)" ::: "memory");
        __hip_atomic_fetch_add(slot, 1u, __ATOMIC_RELAXED, __HIP_MEMORY_SCOPE_AGENT);
        while (__hip_atomic_load(slot, __ATOMIC_RELAXED, __HIP_MEMORY_SCOPE_AGENT) < 16u)
            __builtin_amdgcn_s_sleep(1);
    }
    __syncthreads();
}

// 64 wgs x 512 threads, REGULAR launch (co-resident by capacity).
// seq = wg & 3, row-block rb = wg >> 2 : owns rows l0..l0+3 (l0 = rb*4).
// Register residual: thread t owns (row h = t>>7, col c = t&127).
// GEMM phases: 8-lane-group k-split (coalesced 128B/group) + BATCHED weight
// loads hoisted before the preceding compute so one miss-train per phase.
__global__ __launch_bounds__(NTHR, 1) void fused_kernel(
    const float* __restrict__ mha_in, const int* __restrict__ mask,
    const float* __restrict__ mlp_w1, const float* __restrict__ mlp_b1,
    const float* __restrict__ mlp_w2, const float* __restrict__ mlp_b2,
    const float* __restrict__ in_proj_w, const float* __restrict__ conv_w,
    const float* __restrict__ conv_b, const float* __restrict__ x_proj_w,
    const float* __restrict__ dt_proj_w, const float* __restrict__ dt_proj_b,
    const float* __restrict__ A_log, const float* __restrict__ D_skip,
    const float* __restrict__ out_proj_w, const float* __restrict__ blk_norm_w,
    const float* __restrict__ norm_f_w,
    float* __restrict__ ws, float* __restrict__ out)
{
    const int wg = blockIdx.x;
    const int t  = threadIdx.x;
    const int s  = wg & 3;           // sequence
    const int rb = wg >> 2;          // row-block within seq (0..15)
    const int l0 = rb * 4;           // first owned local row
    const int r0 = s*64 + l0;        // first owned global row
    const int d0 = rb * 16;          // scan channel base
    const int h  = t >> 7;           // owned row 0..3
    const int c  = t & 127;          // owned col
    const int wave = t >> 6;
    const int grp = t >> 3, ln = t & 7;   // GEMM group / lane-in-group

    unsigned* bar = (unsigned*)ws;
    float* xg  = ws + WS_XG;
    float* dtg = ws + WS_DT;
    float* dug = ws + WS_DU;
    float* bcg = ws + WS_BC;
    float* yg  = ws + WS_Y;

    __shared__ float bufX[4][256];   // x (conv input, own rows)
    __shared__ float bufZ[4][256];   // z (computed during scan window)
    __shared__ float bufA[4][256];   // h1 / u (kept live through gate)
    __shared__ float bufG[4][256];   // g = (y + u*Dsk)*silu(z)
    __shared__ float bufB[4][128];   // x_in / hn (own rows)
    __shared__ float bufR[4][128];   // MLP h2 / out-GEMM result rows
    __shared__ float xdS[4][40];
    __shared__ float sdt[64][17];    // staged dt   [l][ch]  (+1 pad: banks)
    __shared__ float sdu[64][17];    // staged dt*u [l][ch]
    __shared__ float sbc[64][33];    // staged B,C  [l][0..15=B,16..31=C]
    __shared__ float part[8];
    __shared__ int   anyv;

    float resid;

    // ===================== MLP preamble (row-local) =====================
    // batch-issue w1+w2 weight loads (address-only, hide under mha load+sync)
    float4 w1v[8], w2v[8];
    {
        #pragma unroll
        for (int pass = 0; pass < 2; ++pass) {
            const int j = pass*64 + grp;
            const float* w1p = mlp_w1 + (size_t)j*128 + ln*4;
            const float* w2p = mlp_w2 + (size_t)j*128 + ln*4;
            #pragma unroll
            for (int i = 0; i < 4; ++i) {
                w1v[pass*4+i] = *(const float4*)&w1p[i*32];
                w2v[pass*4+i] = *(const float4*)&w2p[i*32];
            }
        }
    }
    bufB[h][c] = mha_in[(size_t)s*524288 + (size_t)(l0 + h)*128 + c];
    __syncthreads();
    // ---- h1 = gelu(x @ w1^T + b1) ----
    {
        #pragma unroll
        for (int pass = 0; pass < 2; ++pass) {
            const int j = pass*64 + grp;
            float a0=0.f, a1=0.f, a2=0.f, a3=0.f;
            #pragma unroll
            for (int i = 0; i < 4; ++i) {
                float4 wv = w1v[pass*4+i];
                a0 += dot4(*(const float4*)&bufB[0][ln*4 + i*32], wv);
                a1 += dot4(*(const float4*)&bufB[1][ln*4 + i*32], wv);
                a2 += dot4(*(const float4*)&bufB[2][ln*4 + i*32], wv);
                a3 += dot4(*(const float4*)&bufB[3][ln*4 + i*32], wv);
            }
            a0 = red8(a0); a1 = red8(a1); a2 = red8(a2); a3 = red8(a3);
            if (ln < 4) {
                float v = sel4(ln, a0, a1, a2, a3) + mlp_b1[j];
                bufA[ln][j] = 0.5f*v*(1.0f + erff(v*0.70710678118f));
            }
        }
    }
    __syncthreads();
    // ---- h2 = h1 @ w2^T + b2 -> bufR; resid = bufR[h][c] ----
    {
        #pragma unroll
        for (int pass = 0; pass < 2; ++pass) {
            const int j = pass*64 + grp;
            float a0=0.f, a1=0.f, a2=0.f, a3=0.f;
            #pragma unroll
            for (int i = 0; i < 4; ++i) {
                float4 wv = w2v[pass*4+i];
                a0 += dot4(*(const float4*)&bufA[0][ln*4 + i*32], wv);
                a1 += dot4(*(const float4*)&bufA[1][ln*4 + i*32], wv);
                a2 += dot4(*(const float4*)&bufA[2][ln*4 + i*32], wv);
                a3 += dot4(*(const float4*)&bufA[3][ln*4 + i*32], wv);
            }
            a0 = red8(a0); a1 = red8(a1); a2 = red8(a2); a3 = red8(a3);
            if (ln < 4)
                bufR[ln][j] = sel4(ln, a0, a1, a2, a3) + mlp_b2[j];
        }
    }
    __syncthreads();
    resid = bufR[h][c];
    __syncthreads();

    // ===================== layer loop =====================
    for (int layer = 0; layer < 4; ++layer) {
        unsigned* s1slot = bar + (layer*4 + s)*16;
        unsigned* s2slot = bar + 256 + layer*4 + s;
        unsigned* s3slot = bar + 272 + layer*4 + s;

        // ---- batch-issue in-GEMM x-half weights (hide under rmsnorm) ----
        float4 wx[16];
        {
            #pragma unroll
            for (int pass = 0; pass < 4; ++pass) {
                const float* w = in_proj_w + ((size_t)layer*512 + pass*64 + grp)*128 + ln*4;
                #pragma unroll
                for (int i = 0; i < 4; ++i) wx[pass*4+i] = *(const float4*)&w[i*32];
            }
        }

        // ---- rmsnorm(resid) -> bufB (hn) ----
        {
            float sq = wave_red_sum(resid*resid);
            if ((t & 63) == 0) part[wave] = sq;
        }
        __syncthreads();
        {
            float sr = part[h*2] + part[h*2 + 1];
            float sc = rsqrtf(sr*(1.0f/128.0f) + 1e-5f);
            bufB[h][c] = resid * sc * blk_norm_w[layer*128 + c];
        }
        __syncthreads();

        // ---- in-GEMM x-half: coalesced groups, cols 0..255 -> bufX + xg ----
        {
            #pragma unroll
            for (int pass = 0; pass < 4; ++pass) {
                const int j = pass*64 + grp;
                float a0=0.f, a1=0.f, a2=0.f, a3=0.f;
                #pragma unroll
                for (int i = 0; i < 4; ++i) {
                    float4 wv = wx[pass*4+i];
                    a0 += dot4(*(const float4*)&bufB[0][ln*4 + i*32], wv);
                    a1 += dot4(*(const float4*)&bufB[1][ln*4 + i*32], wv);
                    a2 += dot4(*(const float4*)&bufB[2][ln*4 + i*32], wv);
                    a3 += dot4(*(const float4*)&bufB[3][ln*4 + i*32], wv);
                }
                a0 = red8(a0); a1 = red8(a1); a2 = red8(a2); a3 = red8(a3);
                if (ln < 4) {
                    float v = sel4(ln, a0, a1, a2, a3);
                    bufX[ln][j] = v;
                    astore(&xg[(size_t)(r0 + ln)*256 + j], v);  // halo for rb+1
                }
            }
        }
        // ---- S1: neighbor handshake (conv needs wg rb-1's last 3 rows) ----
        __syncthreads();   // drains all waves' vmcnt -> xg stores at MALL
        if (t == 0) {
            asm volatile("s_waitcnt vmcnt(0)" ::: "memory");
            __hip_atomic_fetch_add(s1slot + rb, 1u, __ATOMIC_RELAXED, __HIP_MEMORY_SCOPE_AGENT);
            if (rb > 0) {
                while (__hip_atomic_load(s1slot + rb - 1, __ATOMIC_RELAXED, __HIP_MEMORY_SCOPE_AGENT) == 0u)
                    __builtin_amdgcn_s_sleep(1);
            }
        }
        __syncthreads();

        // ---- batch-issue xproj weights (hide under conv) ----
        float4 wxp[8];
        if (t < 320) {
            const float* xw = x_proj_w + ((size_t)layer*40 + grp)*256 + ln*4;
            #pragma unroll
            for (int i = 0; i < 8; ++i) wxp[i] = *(const float4*)&xw[i*32];
        }

        // ---- conv + silu -> u in bufA (own rows from LDS, halo via aload) --
        {
            int d = t & 255, half = t >> 8;           // 2 rows per thread
            int rbase = s*64;
            float4 cw = *(const float4*)&conv_w[((size_t)layer*256 + d)*4];
            float cb = conv_b[layer*256 + d];
            if (half == 0) {
                float x0 = (l0-3 >= 0) ? aload(&xg[(size_t)(rbase+l0-3)*256 + d]) : 0.f;
                float x1 = (l0-2 >= 0) ? aload(&xg[(size_t)(rbase+l0-2)*256 + d]) : 0.f;
                float x2 = (l0-1 >= 0) ? aload(&xg[(size_t)(rbase+l0-1)*256 + d]) : 0.f;
                float x3 = bufX[0][d];
                float x4 = bufX[1][d];
                bufA[0][d] = silu_f(cb + cw.x*x0 + cw.y*x1 + cw.z*x2 + cw.w*x3);
                bufA[1][d] = silu_f(cb + cw.x*x1 + cw.y*x2 + cw.z*x3 + cw.w*x4);
            } else {
                float x0 = (l0-1 >= 0) ? aload(&xg[(size_t)(rbase+l0-1)*256 + d]) : 0.f;
                float x1 = bufX[0][d];
                float x2 = bufX[1][d];
                float x3 = bufX[2][d];
                float x4 = bufX[3][d];
                bufA[2][d] = silu_f(cb + cw.x*x0 + cw.y*x1 + cw.z*x2 + cw.w*x3);
                bufA[3][d] = silu_f(cb + cw.x*x1 + cw.y*x2 + cw.z*x3 + cw.w*x4);
            }
        }
        __syncthreads();

        // ---- xproj: coalesced groups, 40 cols, K=256 ; B,C -> bcg inline ---
        if (t < 320) {
            const int jx = grp;                       // 0..39
            float a0=0.f, a1=0.f, a2=0.f, a3=0.f;
            #pragma unroll
            for (int i = 0; i < 8; ++i) {
                float4 wv = wxp[i];
                a0 += dot4(*(const float4*)&bufA[0][ln*4 + i*32], wv);
                a1 += dot4(*(const float4*)&bufA[1][ln*4 + i*32], wv);
                a2 += dot4(*(const float4*)&bufA[2][ln*4 + i*32], wv);
                a3 += dot4(*(const float4*)&bufA[3][ln*4 + i*32], wv);
            }
            a0 = red8(a0); a1 = red8(a1); a2 = red8(a2); a3 = red8(a3);
            if (ln < 4) {
                float v = sel4(ln, a0, a1, a2, a3);
                xdS[ln][jx] = v;
                if (jx >= 8)
                    astore(&bcg[(size_t)(r0+ln)*32 + (jx-8)], v);
            }
        }
        __syncthreads();

        // ---- dt = softplus(...) ; write dt and du = dt*u (write-through) --
        {
            int d = t & 255, half = t >> 8;
            const float* dw = dt_proj_w + ((size_t)layer*256 + d)*8;
            float4 wa = *(const float4*)&dw[0];
            float4 wb = *(const float4*)&dw[4];
            float b = dt_proj_b[layer*256 + d];
            #pragma unroll
            for (int q = 0; q < 2; ++q) {
                int rloc = half*2 + q;
                float4 xa = *(const float4*)&xdS[rloc][0];
                float4 xb = *(const float4*)&xdS[rloc][4];
                float pre = b + dot4(xa, wa) + dot4(xb, wb);
                float sp = (pre > 20.f) ? pre : log1pf(__expf(pre));
                astore(&dtg[(size_t)(r0+rloc)*256 + d], sp);
                astore(&dug[(size_t)(r0+rloc)*256 + d], sp * bufA[rloc][d]);
            }
        }
        seq_barrier(s2slot);   // S2: dt, du, B, C at coherence point

        // ---- stage scan inputs (parallel, all 512 threads) ----
        if (t < 256) {
            int l = t >> 2, q = t & 3;
            const float* p = &dtg[(size_t)(s*64+l)*256 + d0 + q*4];
            sdt[l][q*4]   = aload(p);     sdt[l][q*4+1] = aload(p+1);
            sdt[l][q*4+2] = aload(p+2);   sdt[l][q*4+3] = aload(p+3);
        } else {
            int tt = t - 256; int l = tt >> 2, q = tt & 3;
            const float* p = &dug[(size_t)(s*64+l)*256 + d0 + q*4];
            sdu[l][q*4]   = aload(p);     sdu[l][q*4+1] = aload(p+1);
            sdu[l][q*4+2] = aload(p+2);   sdu[l][q*4+3] = aload(p+3);
        }
        {
            int l = t >> 3, q = t & 7;
            const float* p = &bcg[(size_t)(s*64+l)*32 + q*4];
            sbc[l][q*4]   = aload(p);     sbc[l][q*4+1] = aload(p+1);
            sbc[l][q*4+2] = aload(p+2);   sbc[l][q*4+3] = aload(p+3);
        }
        __syncthreads();

        // ---- scan window: wave0 scans ; waves 4-7 z-GEMM (batched loads) ---
        if (t < 64) {
            const int dloc = t >> 2, sub = t & 3, d = d0 + dloc;
            const float* Ab = A_log + ((size_t)layer*256 + d)*16 + sub*4;
            float A0 = -__expf(Ab[0]), A1 = -__expf(Ab[1]);
            float A2 = -__expf(Ab[2]), A3 = -__expf(Ab[3]);
            float h0 = 0.f, h1v = 0.f, h2v = 0.f, h3v = 0.f;
            #pragma unroll 4
            for (int l = 0; l < 64; ++l) {
                float dtv = sdt[l][dloc];
                float duv = sdu[l][dloc];
                float4 B4, C4;
                B4.x = sbc[l][sub*4];      B4.y = sbc[l][sub*4+1];
                B4.z = sbc[l][sub*4+2];    B4.w = sbc[l][sub*4+3];
                C4.x = sbc[l][16+sub*4];   C4.y = sbc[l][16+sub*4+1];
                C4.z = sbc[l][16+sub*4+2]; C4.w = sbc[l][16+sub*4+3];
                float dA, yp;
                dA = __expf(dtv*A0); h0  = dA*h0  + duv*B4.x; yp  = h0 *C4.x;
                dA = __expf(dtv*A1); h1v = dA*h1v + duv*B4.y; yp += h1v*C4.y;
                dA = __expf(dtv*A2); h2v = dA*h2v + duv*B4.z; yp += h2v*C4.z;
                dA = __expf(dtv*A3); h3v = dA*h3v + duv*B4.w; yp += h3v*C4.w;
                yp += __shfl_xor(yp, 1);
                yp += __shfl_xor(yp, 2);
                if (sub == 0) astore(&yg[(size_t)(s*64+l)*256 + d], yp);
            }
        } else if (t >= 256) {
            // in-GEMM z-half: coalesced groups, two 16-load batches
            const int tz = t - 256, gz = tz >> 3, lz = tz & 7;   // 32 groups
            #pragma unroll
            for (int halfb = 0; halfb < 2; ++halfb) {
                float4 wv[16];
                #pragma unroll
                for (int pass = 0; pass < 4; ++pass) {
                    const int j = (halfb*4 + pass)*32 + gz;
                    const float* w = in_proj_w + ((size_t)layer*512 + 256 + j)*128 + lz*4;
                    #pragma unroll
                    for (int i = 0; i < 4; ++i) wv[pass*4+i] = *(const float4*)&w[i*32];
                }
                #pragma unroll
                for (int pass = 0; pass < 4; ++pass) {
                    const int j = (halfb*4 + pass)*32 + gz;
                    float a0=0.f, a1=0.f, a2=0.f, a3=0.f;
                    #pragma unroll
                    for (int i = 0; i < 4; ++i) {
                        float4 w4 = wv[pass*4+i];
                        a0 += dot4(*(const float4*)&bufB[0][lz*4 + i*32], w4);
                        a1 += dot4(*(const float4*)&bufB[1][lz*4 + i*32], w4);
                        a2 += dot4(*(const float4*)&bufB[2][lz*4 + i*32], w4);
                        a3 += dot4(*(const float4*)&bufB[3][lz*4 + i*32], w4);
                    }
                    a0 += __shfl_xor(a0, 1); a0 += __shfl_xor(a0, 2); a0 += __shfl_xor(a0, 4);
                    a1 += __shfl_xor(a1, 1); a1 += __shfl_xor(a1, 2); a1 += __shfl_xor(a1, 4);
                    a2 += __shfl_xor(a2, 1); a2 += __shfl_xor(a2, 2); a2 += __shfl_xor(a2, 4);
                    a3 += __shfl_xor(a3, 1); a3 += __shfl_xor(a3, 2); a3 += __shfl_xor(a3, 4);
                    if (lz < 4)
                        bufZ[lz][j] = sel4(lz, a0, a1, a2, a3);
                }
            }
        }
        seq_barrier(s3slot);   // S3: y at coherence point (+ bufZ via barrier)

        // ---- batch-issue out-GEMM weights (hide under gate) ----
        float4 wo[16];
        {
            #pragma unroll
            for (int pass = 0; pass < 2; ++pass) {
                const float* w = out_proj_w + ((size_t)layer*128 + pass*64 + grp)*256 + ln*4;
                #pragma unroll
                for (int i = 0; i < 8; ++i) wo[pass*8+i] = *(const float4*)&w[i*32];
            }
        }

        // ---- gate: g = (y + u*Dsk) * silu(z)  (u in bufA, z in bufZ) ----
        {
            int d = t & 255, half = t >> 8;
            float Dsk = D_skip[layer*256 + d];
            #pragma unroll
            for (int q = 0; q < 2; ++q) {
                int rloc = half*2 + q; int r = r0 + rloc;
                float z = bufZ[rloc][d];
                float yv = aload(&yg[(size_t)r*256 + d]) + bufA[rloc][d]*Dsk;
                bufG[rloc][d] = yv * silu_f(z);
            }
        }
        __syncthreads();

        // ---- out-GEMM: coalesced groups, 128 cols, K=256 -> bufR ----
        {
            #pragma unroll
            for (int pass = 0; pass < 2; ++pass) {
                const int j = pass*64 + grp;         // col 0..127
                float a0=0.f, a1=0.f, a2=0.f, a3=0.f;
                #pragma unroll
                for (int i = 0; i < 8; ++i) {
                    float4 wv = wo[pass*8+i];
                    a0 += dot4(*(const float4*)&bufG[0][ln*4 + i*32], wv);
                    a1 += dot4(*(const float4*)&bufG[1][ln*4 + i*32], wv);
                    a2 += dot4(*(const float4*)&bufG[2][ln*4 + i*32], wv);
                    a3 += dot4(*(const float4*)&bufG[3][ln*4 + i*32], wv);
                }
                a0 = red8(a0); a1 = red8(a1); a2 = red8(a2); a3 = red8(a3);
                if (ln < 4)
                    bufR[ln][j] = sel4(ln, a0, a1, a2, a3);
            }
        }
        __syncthreads();
        resid += bufR[h][c];
        __syncthreads();
    }

    // ===================== final: row 63 of each seq =====================
    if (t == 0) anyv = 0;
    __syncthreads();
    if (rb == 15) {
        if (t < 64 && mask[s*4096 + t] != 0) anyv = 1;   // benign race
        float sq = wave_red_sum(resid*resid);
        if ((t & 63) == 0) part[wave] = sq;
    }
    __syncthreads();
    if (rb == 15 && h == 3) {
        float sr = part[6] + part[7];
        float sc = rsqrtf(sr*(1.0f/128.0f) + 1e-5f);
        float o  = resid * sc * norm_f_w[c];
        out[s*128 + c] = anyv ? o : 0.f;
    }
}

// ---------------------------------------------------------------------------
extern "C" void kernel_launch(void* const* d_in, const int* in_sizes, int n_in,
                              void* d_out, int out_size, void* d_ws, size_t ws_size,
                              hipStream_t stream) {
    (void)in_sizes; (void)n_in; (void)out_size; (void)ws_size;
    const float* mha_in     = (const float*)d_in[0];
    const int*   mask       = (const int*)  d_in[1];
    const float* mlp_w1     = (const float*)d_in[2];
    const float* mlp_b1     = (const float*)d_in[3];
    const float* mlp_w2     = (const float*)d_in[4];
    const float* mlp_b2     = (const float*)d_in[5];
    const float* in_proj_w  = (const float*)d_in[6];
    const float* conv_w     = (const float*)d_in[7];
    const float* conv_b     = (const float*)d_in[8];
    const float* x_proj_w   = (const float*)d_in[9];
    const float* dt_proj_w  = (const float*)d_in[10];
    const float* dt_proj_b  = (const float*)d_in[11];
    const float* A_log      = (const float*)d_in[12];
    const float* D_skip     = (const float*)d_in[13];
    const float* out_proj_w = (const float*)d_in[14];
    const float* blk_norm_w = (const float*)d_in[15];
    const float* norm_f_w   = (const float*)d_in[16];
    float* ws  = (float*)d_ws;
    float* out = (float*)d_out;

    // zero the barrier flag slots (graph-capture-safe)
    hipMemsetAsync(d_ws, 0, 2048, stream);

    fused_kernel<<<NWG, NTHR, 0, stream>>>(
        mha_in, mask, mlp_w1, mlp_b1, mlp_w2, mlp_b2,
        in_proj_w, conv_w, conv_b, x_proj_w, dt_proj_w, dt_proj_b,
        A_log, D_skip, out_proj_w, blk_norm_w, norm_f_w, ws, out);
}